// Round 1
// baseline (355.225 us; speedup 1.0000x reference)
//
#include <hip/hip_runtime.h>
#include <hip/hip_bf16.h>
#include <math.h>

typedef __bf16 bf16x8 __attribute__((ext_vector_type(8)));
typedef float f32x4 __attribute__((ext_vector_type(4)));

#define DD 768
#define HH 12
#define MLPD 3072

__device__ __forceinline__ float gelu_exact(float x) {
    return 0.5f * x * (1.0f + erff(x * 0.70710678118654752f));
}

// ---------- weight transpose + fp32->bf16 : Wt[n][k] = bf16(W[k][n]) ----------
__global__ __launch_bounds__(256) void wtrans(const float* __restrict__ W,
                                              __bf16* __restrict__ Wt,
                                              int K, int N) {
    __shared__ float tile[64][65];
    int k0 = blockIdx.x * 64, n0 = blockIdx.y * 64;
    int t = threadIdx.x;
    int tr = t >> 6, tc = t & 63;
#pragma unroll
    for (int i = 0; i < 16; ++i) {
        int row = i * 4 + tr;
        tile[row][tc] = W[(size_t)(k0 + row) * N + n0 + tc];
    }
    __syncthreads();
#pragma unroll
    for (int i = 0; i < 16; ++i) {
        int row = i * 4 + tr;
        Wt[(size_t)(n0 + row) * K + k0 + tc] = (__bf16)tile[tc][row];
    }
}

// ---------- LayerNorm (fp32 in, bf16 out), one wave per row of 768 ----------
__global__ __launch_bounds__(64) void ln_kernel(const float* __restrict__ X,
                                                const float* __restrict__ g,
                                                const float* __restrict__ b,
                                                __bf16* __restrict__ O) {
    int row = blockIdx.x;
    int lane = threadIdx.x;
    const float* xr = X + (size_t)row * DD;
    float4 v[3];
    float s = 0.f, ss = 0.f;
#pragma unroll
    for (int i = 0; i < 3; ++i) {
        v[i] = *reinterpret_cast<const float4*>(&xr[(i * 64 + lane) * 4]);
        s += v[i].x + v[i].y + v[i].z + v[i].w;
        ss += v[i].x * v[i].x + v[i].y * v[i].y + v[i].z * v[i].z + v[i].w * v[i].w;
    }
#pragma unroll
    for (int m = 1; m < 64; m <<= 1) {
        s += __shfl_xor(s, m);
        ss += __shfl_xor(ss, m);
    }
    float mu = s * (1.0f / DD);
    float rstd = rsqrtf(ss * (1.0f / DD) - mu * mu + 1e-5f);
#pragma unroll
    for (int i = 0; i < 3; ++i) {
        int c = (i * 64 + lane) * 4;
        float4 gv = *reinterpret_cast<const float4*>(&g[c]);
        float4 bv = *reinterpret_cast<const float4*>(&b[c]);
        union { __bf16 h[4]; uint2 u; } o;
        o.h[0] = (__bf16)((v[i].x - mu) * rstd * gv.x + bv.x);
        o.h[1] = (__bf16)((v[i].y - mu) * rstd * gv.y + bv.y);
        o.h[2] = (__bf16)((v[i].z - mu) * rstd * gv.z + bv.z);
        o.h[3] = (__bf16)((v[i].w - mu) * rstd * gv.w + bv.w);
        *reinterpret_cast<uint2*>(&O[(size_t)row * DD + c]) = o.u;
    }
}

// ---------- GEMM: C = A(MxK,bf16) * Bt(NxK,bf16)^T + bias, epilogue variants ----------
// EPI 0: q/k -> (b,h,n,f) bf16      EPI 1: v -> (b,h,f,n) bf16
// EPI 2: + resid -> fp32            EPI 3: gelu -> bf16 (stride MLPD)
// EPI 4: gelu + resid -> fp32
template <int EPI>
__global__ __launch_bounds__(256) void gemm_bt(
    const __bf16* __restrict__ A, const __bf16* __restrict__ Bt,
    const float* __restrict__ bias, void* __restrict__ Cout,
    const float* __restrict__ resid, int M, int N, int K) {
    __shared__ __bf16 As[128][72];
    __shared__ __bf16 Bs[128][72];
    const int t = threadIdx.x;
    const int m0 = blockIdx.x * 128, n0 = blockIdx.y * 128;
    const int w = t >> 6, lane = t & 63;
    const int wm = w >> 1, wn = w & 1;
    const int lr = lane & 15, lg = lane >> 4;

    f32x4 acc[4][4] = {};

    for (int k0 = 0; k0 < K; k0 += 64) {
        __syncthreads();
#pragma unroll
        for (int c = 0; c < 4; ++c) {
            int id = c * 256 + t;
            int row = id >> 3, c8 = (id & 7) * 8;
            *reinterpret_cast<uint4*>(&As[row][c8]) =
                *reinterpret_cast<const uint4*>(&A[(size_t)(m0 + row) * K + k0 + c8]);
            *reinterpret_cast<uint4*>(&Bs[row][c8]) =
                *reinterpret_cast<const uint4*>(&Bt[(size_t)(n0 + row) * K + k0 + c8]);
        }
        __syncthreads();
#pragma unroll
        for (int kg = 0; kg < 2; ++kg) {
            bf16x8 af[4], bfr[4];
#pragma unroll
            for (int i = 0; i < 4; ++i)
                af[i] = *reinterpret_cast<const bf16x8*>(&As[wm * 64 + i * 16 + lr][kg * 32 + lg * 8]);
#pragma unroll
            for (int j = 0; j < 4; ++j)
                bfr[j] = *reinterpret_cast<const bf16x8*>(&Bs[wn * 64 + j * 16 + lr][kg * 32 + lg * 8]);
#pragma unroll
            for (int i = 0; i < 4; ++i)
#pragma unroll
                for (int j = 0; j < 4; ++j)
                    acc[i][j] = __builtin_amdgcn_mfma_f32_16x16x32_bf16(af[i], bfr[j], acc[i][j], 0, 0, 0);
        }
    }

#pragma unroll
    for (int i = 0; i < 4; ++i) {
#pragma unroll
        for (int j = 0; j < 4; ++j) {
            int col = n0 + wn * 64 + j * 16 + lr;
            float bc = bias[col];
#pragma unroll
            for (int r = 0; r < 4; ++r) {
                int rr = m0 + wm * 64 + i * 16 + lg * 4 + r;
                float val = acc[i][j][r] + bc;
                if (EPI == 0) {
                    int bI = rr >> 10, n = rr & 1023;
                    int hh = col >> 6, f = col & 63;
                    ((__bf16*)Cout)[(size_t)(((bI * HH + hh) << 10) + n) * 64 + f] = (__bf16)val;
                } else if (EPI == 1) {
                    int bI = rr >> 10, n = rr & 1023;
                    int hh = col >> 6, f = col & 63;
                    ((__bf16*)Cout)[(size_t)(((bI * HH + hh) * 64 + f) << 10) + n] = (__bf16)val;
                } else if (EPI == 2) {
                    ((float*)Cout)[(size_t)rr * DD + col] = val + resid[(size_t)rr * DD + col];
                } else if (EPI == 3) {
                    ((__bf16*)Cout)[(size_t)rr * MLPD + col] = (__bf16)gelu_exact(val);
                } else {
                    ((float*)Cout)[(size_t)rr * DD + col] = gelu_exact(val) + resid[(size_t)rr * DD + col];
                }
            }
        }
    }
}

// ---------- flash attention: 1 block = (b,h) x 64 q-rows; online softmax ----------
__global__ __launch_bounds__(256) void attn_kernel(
    const __bf16* __restrict__ Q, const __bf16* __restrict__ Kg,
    const __bf16* __restrict__ Vt, __bf16* __restrict__ Aout) {
    __shared__ __bf16 Ks[64][72];
    __shared__ __bf16 Vs[64][72];
    __shared__ __bf16 Ps[4][16][72];
    const float scale = 0.036084391824351615f;  // 1/sqrt(768)
    const int qt = blockIdx.x, bh = blockIdx.y;
    const int t = threadIdx.x, w = t >> 6, lane = t & 63;
    const int lr = lane & 15, lg = lane >> 4;
    const size_t bhN = (size_t)bh << 10;
    const int q0 = qt * 64;

    bf16x8 qf[2];
#pragma unroll
    for (int kg = 0; kg < 2; ++kg)
        qf[kg] = *reinterpret_cast<const bf16x8*>(&Q[(bhN + q0 + w * 16 + lr) * 64 + kg * 32 + lg * 8]);

    f32x4 oacc[4] = {};
    float mrow[4], lrow[4];
#pragma unroll
    for (int r = 0; r < 4; ++r) { mrow[r] = -1e30f; lrow[r] = 0.f; }

    for (int kt = 0; kt < 16; ++kt) {
        __syncthreads();
#pragma unroll
        for (int c = 0; c < 2; ++c) {
            int id = c * 256 + t;
            int row = id >> 3, c8 = (id & 7) * 8;
            *reinterpret_cast<uint4*>(&Ks[row][c8]) =
                *reinterpret_cast<const uint4*>(&Kg[(bhN + kt * 64 + row) * 64 + c8]);
            *reinterpret_cast<uint4*>(&Vs[row][c8]) =
                *reinterpret_cast<const uint4*>(&Vt[((size_t)bh * 64 + row) * 1024 + kt * 64 + c8]);
        }
        __syncthreads();

        f32x4 s[4] = {};
#pragma unroll
        for (int kg = 0; kg < 2; ++kg) {
#pragma unroll
            for (int j = 0; j < 4; ++j) {
                bf16x8 kf = *reinterpret_cast<const bf16x8*>(&Ks[j * 16 + lr][kg * 32 + lg * 8]);
                s[j] = __builtin_amdgcn_mfma_f32_16x16x32_bf16(qf[kg], kf, s[j], 0, 0, 0);
            }
        }
#pragma unroll
        for (int r = 0; r < 4; ++r) {
            float s0 = s[0][r] * scale, s1 = s[1][r] * scale;
            float s2 = s[2][r] * scale, s3 = s[3][r] * scale;
            float mx = fmaxf(fmaxf(s0, s1), fmaxf(s2, s3));
#pragma unroll
            for (int m = 1; m < 16; m <<= 1) mx = fmaxf(mx, __shfl_xor(mx, m));
            float mnew = fmaxf(mrow[r], mx);
            float resc = __expf(mrow[r] - mnew);
            mrow[r] = mnew;
            float p0 = __expf(s0 - mnew), p1 = __expf(s1 - mnew);
            float p2 = __expf(s2 - mnew), p3 = __expf(s3 - mnew);
            float psum = p0 + p1 + p2 + p3;
#pragma unroll
            for (int m = 1; m < 16; m <<= 1) psum += __shfl_xor(psum, m);
            lrow[r] = lrow[r] * resc + psum;
#pragma unroll
            for (int j = 0; j < 4; ++j) oacc[j][r] *= resc;
            s[0][r] = p0; s[1][r] = p1; s[2][r] = p2; s[3][r] = p3;
        }
        // C-layout -> A-layout round trip through per-wave LDS
#pragma unroll
        for (int r = 0; r < 4; ++r)
#pragma unroll
            for (int j = 0; j < 4; ++j)
                Ps[w][lg * 4 + r][j * 16 + lr] = (__bf16)s[j][r];
        // same-wave LDS ordering guarantees visibility; no barrier needed
#pragma unroll
        for (int kg = 0; kg < 2; ++kg) {
            bf16x8 pf = *reinterpret_cast<const bf16x8*>(&Ps[w][lr][kg * 32 + lg * 8]);
#pragma unroll
            for (int j = 0; j < 4; ++j) {
                bf16x8 vf = *reinterpret_cast<const bf16x8*>(&Vs[j * 16 + lr][kg * 32 + lg * 8]);
                oacc[j] = __builtin_amdgcn_mfma_f32_16x16x32_bf16(pf, vf, oacc[j], 0, 0, 0);
            }
        }
    }
    const int bI = bh / HH, hh = bh % HH;
#pragma unroll
    for (int r = 0; r < 4; ++r) {
        float inv = 1.0f / lrow[r];
        int qrow = q0 + w * 16 + lg * 4 + r;
        size_t base = ((size_t)(bI << 10) + qrow) * DD + hh * 64;
#pragma unroll
        for (int j = 0; j < 4; ++j)
            Aout[base + j * 16 + lr] = (__bf16)(oacc[j][r] * inv);
    }
}

extern "C" void kernel_launch(void* const* d_in, const int* in_sizes, int n_in,
                              void* d_out, int out_size, void* d_ws, size_t ws_size,
                              hipStream_t stream) {
    const float* x     = (const float*)d_in[0];
    const float* ln1_g = (const float*)d_in[1];
    const float* ln1_b = (const float*)d_in[2];
    const float* Wq    = (const float*)d_in[3];
    const float* bq    = (const float*)d_in[4];
    const float* Wk    = (const float*)d_in[5];
    const float* bk    = (const float*)d_in[6];
    const float* Wv    = (const float*)d_in[7];
    const float* bv    = (const float*)d_in[8];
    const float* Wo    = (const float*)d_in[9];
    const float* bo    = (const float*)d_in[10];
    const float* ln2_g = (const float*)d_in[11];
    const float* ln2_b = (const float*)d_in[12];
    const float* W1    = (const float*)d_in[13];
    const float* b1    = (const float*)d_in[14];
    const float* W2    = (const float*)d_in[15];
    const float* b2    = (const float*)d_in[16];

    char* p = (char*)d_ws;
    auto alloc = [&](size_t bytes) { char* r = p; p += bytes; return r; };
    __bf16* wq_t = (__bf16*)alloc((size_t)768 * 768 * 2);
    __bf16* wk_t = (__bf16*)alloc((size_t)768 * 768 * 2);
    __bf16* wv_t = (__bf16*)alloc((size_t)768 * 768 * 2);
    __bf16* wo_t = (__bf16*)alloc((size_t)768 * 768 * 2);
    __bf16* w1_t = (__bf16*)alloc((size_t)3072 * 768 * 2);
    __bf16* w2_t = (__bf16*)alloc((size_t)768 * 3072 * 2);
    __bf16* h    = (__bf16*)alloc((size_t)8192 * 768 * 2);   // also h2
    float*  outb = (float*) alloc((size_t)8192 * 768 * 4);
    __bf16* q    = (__bf16*)alloc((size_t)8192 * 768 * 2);
    __bf16* kb   = (__bf16*)alloc((size_t)8192 * 768 * 2);
    __bf16* vt   = (__bf16*)alloc((size_t)8192 * 768 * 2);
    __bf16* attn = (__bf16*)alloc((size_t)8192 * 768 * 2);
    __bf16* mid  = q;  // alias: q/k/v dead after attention; mid = 8192*3072*2 = q..attn span

    wtrans<<<dim3(12, 12), 256, 0, stream>>>(Wq, wq_t, 768, 768);
    wtrans<<<dim3(12, 12), 256, 0, stream>>>(Wk, wk_t, 768, 768);
    wtrans<<<dim3(12, 12), 256, 0, stream>>>(Wv, wv_t, 768, 768);
    wtrans<<<dim3(12, 12), 256, 0, stream>>>(Wo, wo_t, 768, 768);
    wtrans<<<dim3(12, 48), 256, 0, stream>>>(W1, w1_t, 768, 3072);
    wtrans<<<dim3(48, 12), 256, 0, stream>>>(W2, w2_t, 3072, 768);

    ln_kernel<<<8192, 64, 0, stream>>>(x, ln1_g, ln1_b, h);
    gemm_bt<0><<<dim3(64, 6), 256, 0, stream>>>(h, wq_t, bq, q, nullptr, 8192, 768, 768);
    gemm_bt<0><<<dim3(64, 6), 256, 0, stream>>>(h, wk_t, bk, kb, nullptr, 8192, 768, 768);
    gemm_bt<1><<<dim3(64, 6), 256, 0, stream>>>(h, wv_t, bv, vt, nullptr, 8192, 768, 768);
    attn_kernel<<<dim3(16, 96), 256, 0, stream>>>(q, kb, vt, attn);
    gemm_bt<2><<<dim3(64, 6), 256, 0, stream>>>(attn, wo_t, bo, outb, x, 8192, 768, 768);
    ln_kernel<<<8192, 64, 0, stream>>>(outb, ln2_g, ln2_b, h);
    gemm_bt<3><<<dim3(64, 24), 256, 0, stream>>>(h, w1_t, b1, mid, nullptr, 8192, 3072, 768);
    gemm_bt<4><<<dim3(64, 6), 256, 0, stream>>>(mid, w2_t, b2, (float*)d_out, outb, 8192, 768, 3072);
}